// Round 7
// baseline (4694.604 us; speedup 1.0000x reference)
//
#include <hip/hip_runtime.h>
#include <hip/hip_fp16.h>
#include <math.h>

// AcousticRadianceTransfer v7 — freq-domain LDS SpMV, scheduled & pipelined.
// vs v6: (1) per-thread edge lists bank-sorted + lane-staggered (kills LDS
// conflicts), (2) state f16c with rho=1/8 per-bounce rescale -> v_dot2_f32_f16
// pairs halve VALU, (3) depth-1 register prefetch of edge stream, (4) setup
// parallelized (24-block build; dftB grid (u,chunk)-major for L2 reuse).

static constexpr float kSR = 16000.0f;
static constexpr int   kL = 1600;
static constexpr int   kNRad = 24000;
static constexpr int   kNNZ = 480000;
static constexpr int   kNPatch = 256;
static constexpr int   kNF = 801;
static constexpr int   kNB = 8;
static constexpr float kLogGamma = -6.907755278982137f; // ln(0.001)
static constexpr float kRho = 0.125f;                   // state rescale/bounce

using u32 = unsigned int;
using u16 = unsigned short;

typedef _Float16 half2v __attribute__((ext_vector_type(2)));

__device__ __forceinline__ u32 pk_h(float re, float im) {
    return ((u32)__half_as_ushort(__float2half(im)) << 16)
         | (u32)__half_as_ushort(__float2half(re));
}
__device__ __forceinline__ float h2f(u32 bits) {
    return __half2float(__ushort_as_half((u16)bits));
}
__device__ __forceinline__ u32 permb(u32 hi, u32 lo, u32 sel) {
#if __has_builtin(__builtin_amdgcn_perm)
    return __builtin_amdgcn_perm(hi, lo, sel);
#else
    unsigned long long v = ((unsigned long long)hi << 32) | lo;
    u32 r = 0;
    for (int i = 0; i < 4; ++i)
        r |= ((u32)(v >> (8 * ((sel >> (8 * i)) & 7))) & 0xffu) << (8 * i);
    return r;
#endif
}
__device__ __forceinline__ float fdot2f(u32 a, u32 b, float c) {
#if __has_builtin(__builtin_amdgcn_fdot2)
    return __builtin_amdgcn_fdot2(__builtin_bit_cast(half2v, a),
                                  __builtin_bit_cast(half2v, b), c, false);
#else
    return c + h2f(a & 0xffffu) * h2f(b & 0xffffu) + h2f(a >> 16) * h2f(b >> 16);
#endif
}

// ---------------- CSR build + degree sort (descending) ----------------------

__global__ void k_hist(const int* __restrict__ row, int* __restrict__ cnt) {
    int e = blockIdx.x * 256 + threadIdx.x;
    if (e < kNNZ) atomicAdd(&cnt[row[e]], 1);
}

__global__ void k_deghist(const int* __restrict__ cnt, int* __restrict__ degcnt) {
    int i = blockIdx.x * 256 + threadIdx.x;
    if (i < kNRad) atomicAdd(&degcnt[min(cnt[i], 63)], 1);
}

__global__ void k_degscan(int* __restrict__ degcnt, int* __restrict__ degcur) {
    if (threadIdx.x == 0) {
        int s = 0;
        for (int b = 63; b >= 0; --b) {
            int c = degcnt[b];
            degcnt[b] = s; degcur[b] = s; s += c;
        }
    }
}

__global__ void k_perm(const int* __restrict__ cnt, int* __restrict__ degcur,
                       int* __restrict__ perm, int* __restrict__ iperm) {
    int i = blockIdx.x * 256 + threadIdx.x;
    if (i >= kNRad) return;
    int b = min(cnt[i], 63);
    int pos = atomicAdd(&degcur[b], 1);
    perm[pos] = i;
    iperm[i] = pos;
}

__global__ void k_scan2(const int* __restrict__ cnt, const int* __restrict__ perm,
                        int* __restrict__ rowptr, int* __restrict__ cursor) {
    __shared__ int s[256];
    __shared__ int carry_s;
    int tid = threadIdx.x;
    if (tid == 0) carry_s = 0;
    __syncthreads();
    for (int base = 0; base < kNRad; base += 256) {
        int i = base + tid;
        int v = (i < kNRad) ? cnt[perm[i]] : 0;
        s[tid] = v;
        __syncthreads();
        for (int off = 1; off < 256; off <<= 1) {
            int t = (tid >= off) ? s[tid - off] : 0;
            __syncthreads();
            s[tid] += t;
            __syncthreads();
        }
        int incl = s[tid];
        int c = carry_s;
        if (i < kNRad) {
            int ex = c + incl - v;
            rowptr[i] = ex;
            cursor[i] = ex;
        }
        __syncthreads();
        if (tid == 255) carry_s = c + incl;
        __syncthreads();
    }
    if (tid == 0) rowptr[kNRad] = carry_s;
}

__global__ void k_scatter(const float* __restrict__ absorb,
                          const float* __restrict__ scat,
                          const float* __restrict__ basis,
                          const int* __restrict__ row,
                          const int* __restrict__ col,
                          const int* __restrict__ rid,
                          const int* __restrict__ iperm,
                          int* __restrict__ cursor,
                          u32* __restrict__ epack) {
    int e = blockIdx.x * 256 + threadIdx.x;
    if (e >= kNNZ) return;
    int rd = rid[e];
    float v = (scat[rd] * basis[e] + scat[kNPatch + rd] * basis[kNNZ + e]) * absorb[rd];
    int p = iperm[row[e]];
    int pos = atomicAdd(&cursor[p], 1);
    u32 hv = (u32)__half_as_ushort(__float2half(v));
    epack[pos] = (hv << 16) | (u32)col[e];
}

__global__ void k_decay(const int* __restrict__ delay,
                        float* __restrict__ decay, int* __restrict__ dmod) {
    int i = blockIdx.x * 256 + threadIdx.x;
    if (i >= kNRad) return;
    int d = delay[i];
    decay[i] = expf(kLogGamma * (float)d / kSR);
    dmod[i] = d % kL;
}

// ---- per-(stratum,thread) offsets + rowmeta (pair units, pad to 4 edges) ---

__global__ void k_boff(const int* __restrict__ rowptr, const int* __restrict__ perm,
                       u32* __restrict__ rowmeta, int* __restrict__ offT) {
    int t = threadIdx.x;   // 1024, one block
    int off = 0;
    for (int i = 0; i < 24; ++i) {
        int sidx = i * 1024 + ((i & 1) ? (1023 - t) : t);
        int deg = 0, orow = 0;
        if (sidx < kNRad) {
            deg = rowptr[sidx + 1] - rowptr[sidx];
            orow = perm[sidx];
        }
        int nit = (deg + 3) >> 2;
        rowmeta[i * 1024 + t] = ((u32)nit << 16) | (u32)orow;
        offT[i * 1024 + t] = off;
        off += nit * 2;   // pairs
    }
}

// ---- bank-sorted, lane-staggered, pair-packed edge emission ----------------

__global__ void k_bcopy(const int* __restrict__ rowptr,
                        const u32* __restrict__ epack,
                        const int* __restrict__ offT,
                        u32* __restrict__ ecol2, u32* __restrict__ eval2) {
    int i = blockIdx.x, t = threadIdx.x;
    int sidx = i * 1024 + ((i & 1) ? (1023 - t) : t);
    if (sidx >= kNRad) return;
    int e0 = rowptr[sidx];
    int deg = rowptr[sidx + 1] - e0;
    if (deg == 0) return;
    int nit = (deg + 3) >> 2;
    int total = nit * 4;
    int rot = ((t & 63) * deg) >> 6;
    int jp0 = offT[i * 1024 + t];
    u32 cw = 0, vw = 0;
    int cnt = 0;
    auto emit = [&](u32 col, u32 val) {
        if (cnt & 1) {
            cw |= col << 16; vw |= val << 16;
            int p = jp0 + (cnt >> 1);
            ecol2[(size_t)p * 1024 + t] = cw;
            eval2[(size_t)p * 1024 + t] = vw;
        } else { cw = col; vw = val; }
        ++cnt;
    };
    int s = 0;
    for (int b = 0; b < 32; ++b)
        for (int e = 0; e < deg; ++e) {
            u32 u = epack[e0 + e];
            u32 col = u & 0xffffu;
            if ((int)(col & 31u) != b) continue;
            if (s >= rot) emit(col, u >> 16);
            ++s;
        }
    s = 0;
    for (int b = 0; b < 32; ++b)
        for (int e = 0; e < deg; ++e) {
            u32 u = epack[e0 + e];
            u32 col = u & 0xffffu;
            if ((int)(col & 31u) != b) continue;
            if (s < rot) emit(col, u >> 16);
            ++s;
        }
    for (int p = deg; p < total; ++p) emit(0u, 0u);
}

// ---- stage A: 25-point DFTs, f16c out ----

__global__ __launch_bounds__(256) void k_dftA(const float* __restrict__ rad,
                                              u32* __restrict__ G) {
    __shared__ float twc[625], tws[625];
    int tid = threadIdx.x;
    for (int idx = tid; idx < 625; idx += 256) {
        int u = idx / 25, q = idx - u * 25;
        float a = 2.0f * (float)((u * q) % 25) / 25.0f;
        twc[idx] = cospif(a);
        tws[idx] = -sinpif(a);
    }
    __syncthreads();
    int wv = tid >> 6, lane = tid & 63;
    int r = blockIdx.x * 4 + wv;
    float xq[25];
#pragma unroll
    for (int q = 0; q < 25; ++q) {
        int m = q * 64 + lane;
        xq[q] = rad[(size_t)r * kL + m] * expf(kLogGamma * (float)m / kSR);
    }
#pragma unroll 1
    for (int u = 0; u < 25; ++u) {
        float re = 0.f, im = 0.f;
#pragma unroll
        for (int q = 0; q < 25; ++q) {
            re = fmaf(xq[q], twc[u * 25 + q], re);
            im = fmaf(xq[q], tws[u * 25 + q], im);
        }
        G[((size_t)u * kNRad + r) * 64 + lane] = pk_h(re, im);
    }
}

// ---- stage B: 64-term twiddle sums, (u,chunk)-major grid for L2 reuse ------

__global__ __launch_bounds__(256) void k_dftB(const u32* __restrict__ G,
                                              u32* __restrict__ XF) {
    int bid = blockIdx.x;            // 25*4*33 = 3300
    int u = bid / 132;
    int rem = bid - u * 132;
    int chunk = rem / 33, jj = rem - chunk * 33;
    int k = u + 25 * jj;
    if (k > 800) return;
    __shared__ float twc[64], tws[64];
    int tid = threadIdx.x;
    if (tid < 64) {
        int m = (k * tid) % kL;
        float a = (float)m / 800.0f;
        twc[tid] = cospif(a);
        tws[tid] = -sinpif(a);
    }
    __syncthreads();
    for (int rr = tid; rr < 6000; rr += 256) {
        int r = chunk * 6000 + rr;
        const uint4* gp = (const uint4*)(G + ((size_t)u * kNRad + r) * 64);
        float re = 0.f, im = 0.f;
#pragma unroll 4
        for (int jw = 0; jw < 16; ++jw) {
            uint4 q = gp[jw];
            u32 zz[4] = {q.x, q.y, q.z, q.w};
#pragma unroll
            for (int c2 = 0; c2 < 4; ++c2) {
                int ss = jw * 4 + c2;
                float gr = h2f(zz[c2] & 0xffffu), gi = h2f(zz[c2] >> 16);
                float c = twc[ss], sn = tws[ss];
                re += gr * c - gi * sn;
                im += gr * sn + gi * c;
            }
        }
        XF[(size_t)k * kNRad + r] = pk_h(re, im);
    }
}

// ---- core: per-frequency 8-bounce LDS SpMV (f16c, fdot2, prefetched) -------

__global__ __launch_bounds__(1024) void k_freq(const u32* __restrict__ XF,
                                               const u32* __restrict__ rowmeta,
                                               const u32* __restrict__ ecol2,
                                               const u32* __restrict__ eval2,
                                               const float* __restrict__ w,
                                               const float* __restrict__ decay,
                                               const int* __restrict__ dmod,
                                               float* __restrict__ yhat) {
    extern __shared__ u32 lds[];
    u32* ldsx = lds;                         // 24000 x f16c
    float* red = (float*)(lds + kNRad);
    int k = blockIdx.x, tid = threadIdx.x;
    float yre = 0.f, yim = 0.f;

    for (int r = tid; r < kNRad; r += 1024) {
        u32 xz = XF[(size_t)k * kNRad + r];
        float xr = h2f(xz & 0xffffu), xi = h2f(xz >> 16);
        float wr = w[r];
        yre = fmaf(wr, xr, yre); yim = fmaf(wr, xi, yim);
        int m = (dmod[r] * k) % kL;
        float a = (float)m * (1.0f / 800.0f);
        float c = cospif(a), sn = sinpif(a);
        float dc = decay[r];
        float dre = dc * c, dim = -dc * sn;
        ldsx[r] = pk_h(dre * xr - dim * xi, dre * xi + dim * xr);
    }
    __syncthreads();

    float cwS = 1.0f;
    for (int b = 0; b < kNB; ++b) {
        float nzr[24], nzi[24];
        int jp = 0;
#pragma unroll
        for (int i = 0; i < 24; ++i) {
            u32 meta = rowmeta[i * 1024 + tid];
            int nit = (int)(meta >> 16);
            int orow = (int)(meta & 0xffffu);
            float ar = 0.f, ai = 0.f;
            u32 ca = 0, cb = 0, va = 0, vb = 0;
            if (nit > 0) {
                ca = ecol2[(size_t)(jp + 0) * 1024 + tid];
                cb = ecol2[(size_t)(jp + 1) * 1024 + tid];
                va = eval2[(size_t)(jp + 0) * 1024 + tid];
                vb = eval2[(size_t)(jp + 1) * 1024 + tid];
            }
            for (int it = 0; it < nit; ++it) {
                u32 na = 0, nb = 0, wa = 0, wb = 0;
                int jn = jp + 2;
                if (it + 1 < nit) {
                    na = ecol2[(size_t)(jn + 0) * 1024 + tid];
                    nb = ecol2[(size_t)(jn + 1) * 1024 + tid];
                    wa = eval2[(size_t)(jn + 0) * 1024 + tid];
                    wb = eval2[(size_t)(jn + 1) * 1024 + tid];
                }
                u32 z0 = ldsx[ca & 0xffffu];
                u32 z1 = ldsx[ca >> 16];
                u32 z2 = ldsx[cb & 0xffffu];
                u32 z3 = ldsx[cb >> 16];
                u32 xr01 = permb(z1, z0, 0x05040100u);
                u32 xi01 = permb(z1, z0, 0x07060302u);
                u32 xr23 = permb(z3, z2, 0x05040100u);
                u32 xi23 = permb(z3, z2, 0x07060302u);
                ar = fdot2f(va, xr01, ar);
                ai = fdot2f(va, xi01, ai);
                ar = fdot2f(vb, xr23, ar);
                ai = fdot2f(vb, xi23, ai);
                ca = na; cb = nb; va = wa; vb = wb;
                jp = jn;
            }
            float wc = w[orow] * cwS;
            yre = fmaf(wc, ar, yre); yim = fmaf(wc, ai, yim);
            int m = (dmod[orow] * k) % kL;
            float a = (float)m * (1.0f / 800.0f);
            float c = cospif(a), sn = sinpif(a);
            float dc = decay[orow] * kRho;
            float dre = dc * c, dim = -dc * sn;
            nzr[i] = dre * ar - dim * ai;
            nzi[i] = dre * ai + dim * ar;
        }
        cwS *= (1.0f / kRho);
        __syncthreads();
#pragma unroll
        for (int i = 0; i < 24; ++i) {
            if ((i < 23) || (tid >= 576)) {
                u32 meta = rowmeta[i * 1024 + tid];
                ldsx[meta & 0xffffu] = pk_h(nzr[i], nzi[i]);
            }
        }
        __syncthreads();
    }

#pragma unroll
    for (int m = 1; m <= 32; m <<= 1) {
        yre += __shfl_xor(yre, m, 64);
        yim += __shfl_xor(yim, m, 64);
    }
    int wv = tid >> 6, lane = tid & 63;
    if (lane == 0) { red[wv * 2] = yre; red[wv * 2 + 1] = yim; }
    __syncthreads();
    if (tid == 0) {
        float sr = 0.f, si = 0.f;
        for (int i = 0; i < 16; ++i) { sr += red[i * 2]; si += red[i * 2 + 1]; }
        yhat[2 * k] = sr;
        yhat[2 * k + 1] = si;
    }
}

// ---- finish: irfft(yhat)[n] * exp(env)/fsm ---------------------------------

__global__ void k_final(const float* __restrict__ yhat,
                        const float* __restrict__ env,
                        float* __restrict__ out) {
    int n = blockIdx.x * 256 + threadIdx.x;
    if (n >= kL) return;
    float acc = yhat[0];
    acc += (n & 1) ? -yhat[1600] : yhat[1600];
    for (int k = 1; k < 800; ++k) {
        int m = (k * n) % kL;
        float a = (float)m / 800.0f;
        float c = cospif(a), s = sinpif(a);
        acc += 2.0f * (yhat[2 * k] * c - yhat[2 * k + 1] * s);
    }
    acc *= (1.0f / 1600.0f);
    out[n] = acc * expf(env[n] - kLogGamma * (float)n / kSR);
}

extern "C" void kernel_launch(void* const* d_in, const int* in_sizes, int n_in,
                              void* d_out, int out_size, void* d_ws, size_t ws_size,
                              hipStream_t stream) {
    const float* absorb = (const float*)d_in[0];
    const float* scat   = (const float*)d_in[1];
    const float* rad    = (const float*)d_in[2];
    const float* w      = (const float*)d_in[3];
    const float* env    = (const float*)d_in[4];
    const float* basis  = (const float*)d_in[5];
    const int*   srow   = (const int*)d_in[6];
    const int*   scol   = (const int*)d_in[7];
    const int*   srid   = (const int*)d_in[8];
    const int*   delay  = (const int*)d_in[9];

    char* ws = (char*)d_ws;
    size_t off = 0;
    auto alloc = [&](size_t bytes) -> char* {
        char* p = ws + off;
        off += (bytes + 255) & ~size_t(255);
        return p;
    };
    u32*  G      = (u32*)alloc((size_t)25 * kNRad * 64 * 4);   // 153.6 MB
    u32*  XF     = (u32*)alloc((size_t)kNF * kNRad * 4);       // 76.9 MB
    u32*  ecol2  = (u32*)alloc((size_t)768 * 1024 * 4);        // 3 MB
    u32*  eval2  = (u32*)alloc((size_t)768 * 1024 * 4);        // 3 MB
    u32*  epack  = (u32*)alloc((size_t)kNNZ * 4);
    u32*  rowmeta= (u32*)alloc((size_t)24 * 1024 * 4);
    int*  offT   = (int*)alloc((size_t)24 * 1024 * 4);
    float* yhat  = (float*)alloc((size_t)1602 * 4);
    int*  rowptr = (int*)alloc((size_t)(kNRad + 1) * 4);
    int*  cursor = (int*)alloc((size_t)kNRad * 4);
    int*  cnt    = (int*)alloc((size_t)kNRad * 4);
    int*  perm   = (int*)alloc((size_t)kNRad * 4);
    int*  iperm  = (int*)alloc((size_t)kNRad * 4);
    float* decay = (float*)alloc((size_t)kNRad * 4);
    int*  dmod   = (int*)alloc((size_t)kNRad * 4);
    int*  degcnt = (int*)alloc(64 * 4);
    int*  degcur = (int*)alloc(64 * 4);
    (void)ws_size; (void)in_sizes; (void)n_in; (void)out_size; (void)scol;

    hipMemsetAsync(cnt, 0, (size_t)kNRad * 4, stream);
    hipMemsetAsync(degcnt, 0, 64 * 4, stream);

    k_hist<<<(kNNZ + 255) / 256, 256, 0, stream>>>(srow, cnt);
    k_deghist<<<(kNRad + 255) / 256, 256, 0, stream>>>(cnt, degcnt);
    k_degscan<<<1, 64, 0, stream>>>(degcnt, degcur);
    k_perm<<<(kNRad + 255) / 256, 256, 0, stream>>>(cnt, degcur, perm, iperm);
    k_scan2<<<1, 256, 0, stream>>>(cnt, perm, rowptr, cursor);
    k_decay<<<(kNRad + 255) / 256, 256, 0, stream>>>(delay, decay, dmod);
    k_scatter<<<(kNNZ + 255) / 256, 256, 0, stream>>>(absorb, scat, basis, srow,
                                                      scol, srid, iperm, cursor, epack);
    k_boff<<<1, 1024, 0, stream>>>(rowptr, perm, rowmeta, offT);
    k_bcopy<<<24, 1024, 0, stream>>>(rowptr, epack, offT, ecol2, eval2);

    k_dftA<<<kNRad / 4, 256, 0, stream>>>(rad, G);
    k_dftB<<<3300, 256, 0, stream>>>(G, XF);

    hipFuncSetAttribute((const void*)k_freq,
                        hipFuncAttributeMaxDynamicSharedMemorySize, 98304);
    size_t ldsbytes = (size_t)kNRad * 4 + 256;
    k_freq<<<kNF, 1024, ldsbytes, stream>>>(XF, rowmeta, ecol2, eval2,
                                            w, decay, dmod, yhat);

    k_final<<<(kL + 255) / 256, 256, 0, stream>>>(yhat, env, (float*)d_out);
}

// Round 8
// 2753.604 us; speedup vs baseline: 1.7049x; 1.7049x over previous
//
#include <hip/hip_runtime.h>
#include <hip/hip_fp16.h>
#include <math.h>

// AcousticRadianceTransfer v8 — v5 time-domain structure (proven 1646 us)
// + ONE experiment: nontemporal (L1-bypass) gather loads.
// Rounds 2-5 pinned at ~0.1 random-128B-lines/cyc/CU regardless of bytes,
// slicing, or MLP -> hypothesis: per-CU L1 miss-handling serialization
// (all gathers miss the 32KB L1; 3MB slice working set). nt loads skip L1.
// Also: slice-24 double-work blocks moved to phase 0 (tail hidden).

static constexpr float kSR = 16000.0f;
static constexpr int   kL = 1600;
static constexpr int   kNRad = 24000;
static constexpr int   kNNZ = 480000;
static constexpr int   kNPatch = 256;
static constexpr int   kNBounce = 8;
static constexpr int   kSW = 64;           // samples per slice
static constexpr int   kNS = 25;           // slices
static constexpr int   kNRB = 750;         // row-blocks of 32 rows
static constexpr float kLogGamma = -6.907755278982137f; // ln(0.001)

using u32 = unsigned int;
typedef u32 uv4 __attribute__((ext_vector_type(4)));

__device__ __forceinline__ unsigned short f2bf(float f) {
    u32 u = __float_as_uint(f);
    u32 r = u + 0x7fffu + ((u >> 16) & 1u);   // RTN-even
    return (unsigned short)(r >> 16);
}
__device__ __forceinline__ float bflo(u32 w) { return __uint_as_float(w << 16); }
__device__ __forceinline__ float bfhi(u32 w) { return __uint_as_float(w & 0xffff0000u); }
__device__ __forceinline__ float h2f(u32 hv) {
    return __half2float(__ushort_as_half((unsigned short)hv));
}
__device__ __forceinline__ uv4 ldnt4(const unsigned short* p) {
    return __builtin_nontemporal_load((const uv4*)p);   // global_load_dwordx4 nt
}
__device__ __forceinline__ void fma8(float (&a)[8], float v, const uv4 q) {
    a[0] = fmaf(v, bflo(q[0]), a[0]);
    a[1] = fmaf(v, bfhi(q[0]), a[1]);
    a[2] = fmaf(v, bflo(q[1]), a[2]);
    a[3] = fmaf(v, bfhi(q[1]), a[3]);
    a[4] = fmaf(v, bflo(q[2]), a[4]);
    a[5] = fmaf(v, bfhi(q[2]), a[5]);
    a[6] = fmaf(v, bflo(q[3]), a[6]);
    a[7] = fmaf(v, bfhi(q[3]), a[7]);
}

// ---------------- CSR build + degree sort ----------------

__global__ void k_hist(const int* __restrict__ row, int* __restrict__ cnt) {
    int e = blockIdx.x * 256 + threadIdx.x;
    if (e < kNNZ) atomicAdd(&cnt[row[e]], 1);
}

__global__ void k_deghist(const int* __restrict__ cnt, int* __restrict__ degcnt) {
    int i = blockIdx.x * 256 + threadIdx.x;
    if (i < kNRad) atomicAdd(&degcnt[min(cnt[i], 63)], 1);
}

__global__ void k_degscan(int* __restrict__ degcnt, int* __restrict__ degcur) {
    if (threadIdx.x == 0) {
        int s = 0;
        for (int b = 0; b < 64; ++b) {
            int c = degcnt[b];
            degcnt[b] = s;
            degcur[b] = s;
            s += c;
        }
    }
}

__global__ void k_perm(const int* __restrict__ cnt, int* __restrict__ degcur,
                       int* __restrict__ perm, int* __restrict__ iperm) {
    int i = blockIdx.x * 256 + threadIdx.x;
    if (i >= kNRad) return;
    int b = min(cnt[i], 63);
    int pos = atomicAdd(&degcur[b], 1);
    perm[pos] = i;
    iperm[i] = pos;
}

__global__ void k_scan2(const int* __restrict__ cnt, const int* __restrict__ perm,
                        int* __restrict__ rowptr, int* __restrict__ cursor) {
    __shared__ int s[256];
    __shared__ int carry_s;
    int tid = threadIdx.x;
    if (tid == 0) carry_s = 0;
    __syncthreads();
    for (int base = 0; base < kNRad; base += 256) {
        int i = base + tid;
        int v = (i < kNRad) ? cnt[perm[i]] : 0;
        s[tid] = v;
        __syncthreads();
        for (int off = 1; off < 256; off <<= 1) {
            int t = (tid >= off) ? s[tid - off] : 0;
            __syncthreads();
            s[tid] += t;
            __syncthreads();
        }
        int incl = s[tid];
        int c = carry_s;
        if (i < kNRad) {
            int ex = c + incl - v;
            rowptr[i] = ex;
            cursor[i] = ex;
        }
        __syncthreads();
        if (tid == 255) carry_s = c + incl;
        __syncthreads();
    }
    if (tid == 0) rowptr[kNRad] = carry_s;
}

__global__ void k_scatter(const float* __restrict__ absorb,
                          const float* __restrict__ scat,
                          const float* __restrict__ basis,
                          const int* __restrict__ row,
                          const int* __restrict__ col,
                          const int* __restrict__ rid,
                          const int* __restrict__ iperm,
                          int* __restrict__ cursor,
                          u32* __restrict__ epack) {
    int e = blockIdx.x * 256 + threadIdx.x;
    if (e >= kNNZ) return;
    int rd = rid[e];
    float v = (scat[rd] * basis[e] + scat[kNPatch + rd] * basis[kNNZ + e]) * absorb[rd];
    int p = iperm[row[e]];
    int pos = atomicAdd(&cursor[p], 1);
    u32 hv = (u32)__half_as_ushort(__float2half(v));
    epack[pos] = (hv << 16) | (u32)col[e];
}

__global__ void k_decay(const int* __restrict__ delay,
                        float* __restrict__ decay, int* __restrict__ dmod) {
    int i = blockIdx.x * 256 + threadIdx.x;
    if (i >= kNRad) return;
    int d = delay[i];
    decay[i] = expf(kLogGamma * (float)d / kSR);
    dmod[i] = d % kL;
}

// ---------------- init: slice-major bf16 shifted state + ypartA --------------

__global__ __launch_bounds__(64) void k_init(const float* __restrict__ rad,
                                             const float* __restrict__ w,
                                             const float* __restrict__ decay,
                                             const int* __restrict__ dmod,
                                             unsigned short* __restrict__ outS,
                                             float* __restrict__ ypartA) {
    int bid = blockIdx.x;
    int lane = threadIdx.x;
    const size_t SS = (size_t)kNRad * kSW;
    for (int k = 0; k < kNS; ++k) {
        int m = k * kSW + lane;
        float fs = expf(kLogGamma * (float)m / kSR);
        float y = 0.0f;
#pragma unroll
        for (int g = 0; g < 8; ++g) {
            int r = bid * 8 + g;
            float v = rad[(size_t)r * kL + m] * fs;
            y = fmaf(w[r], v, y);
            int n = m + dmod[r];
            if (n >= kL) n -= kL;
            outS[(size_t)(n >> 6) * SS + (size_t)r * kSW + (n & 63)] =
                f2bf(decay[r] * v);
        }
        ypartA[(size_t)bid * kL + m] = y;
    }
}

// ---------------- one bounce, phase-major, MLP-4, nt gathers ----------------
// bid = (phase*kNRB + rb)*8 + x ; slice S = x + 8*phase (phase 0..2).
// Phase-0 blocks with rb&7==x also do slice 24 (phase 0 launches first ->
// the double-work blocks start earliest, hiding the tail).

__global__ __launch_bounds__(256) void k_bounce(const unsigned short* __restrict__ inS,
                                                unsigned short* __restrict__ outS,
                                                float* __restrict__ ypart,
                                                const u32* __restrict__ epack,
                                                const int* __restrict__ rowptr,
                                                const int* __restrict__ perm,
                                                const float* __restrict__ w,
                                                const float* __restrict__ decay,
                                                const int* __restrict__ dmod) {
    int bid = blockIdx.x;
    int x = bid & 7;
    int t = bid >> 3;
    int phase = t / kNRB;
    int rb = t - phase * kNRB;
    int tid = threadIdx.x, wv = tid >> 6, lane = tid & 63;
    int g = lane >> 3, p = lane & 7;
    int r = rb * 32 + wv * 8 + g;
    int e0 = rowptr[r], e1 = rowptr[r + 1];
    const size_t SS = (size_t)kNRad * kSW;
    __shared__ float tb[4][8][64];

    auto do_slice = [&](int S) {
        const unsigned short* b = inS + (size_t)S * SS + (size_t)p * 8;
        float acc[8] = {0, 0, 0, 0, 0, 0, 0, 0};
        int e = e0;
        for (; e + 4 <= e1; e += 4) {
            u32 u0 = epack[e];
            u32 u1 = epack[e + 1];
            u32 u2 = epack[e + 2];
            u32 u3 = epack[e + 3];
            uv4 q0 = ldnt4(b + (size_t)(u0 & 0xffffu) * kSW);
            uv4 q1 = ldnt4(b + (size_t)(u1 & 0xffffu) * kSW);
            uv4 q2 = ldnt4(b + (size_t)(u2 & 0xffffu) * kSW);
            uv4 q3 = ldnt4(b + (size_t)(u3 & 0xffffu) * kSW);
            fma8(acc, h2f(u0 >> 16), q0);
            fma8(acc, h2f(u1 >> 16), q1);
            fma8(acc, h2f(u2 >> 16), q2);
            fma8(acc, h2f(u3 >> 16), q3);
        }
        for (; e < e1; ++e) {
            u32 u = epack[e];
            uv4 q = ldnt4(b + (size_t)(u & 0xffffu) * kSW);
            fma8(acc, h2f(u >> 16), q);
        }
        // LDS transpose -> wave-contiguous shifted+decayed stores + y reduce
#pragma unroll
        for (int i = 0; i < 8; ++i) tb[wv][g][p * 8 + i] = acc[i];
        float yk = 0.0f;
#pragma unroll
        for (int g2 = 0; g2 < 8; ++g2) {
            int o2 = perm[rb * 32 + wv * 8 + g2];
            float val = tb[wv][g2][lane];
            yk = fmaf(w[o2], val, yk);
            int n = S * kSW + lane + dmod[o2];
            if (n >= kL) n -= kL;
            if (n >= kL) n -= kL;
            outS[(size_t)(n >> 6) * SS + (size_t)o2 * kSW + (n & 63)] =
                f2bf(decay[o2] * val);
        }
        ypart[((size_t)(rb * 4 + wv)) * kL + S * kSW + lane] += yk;
    };

    do_slice(x + 8 * phase);
    if (phase == 0 && ((rb & 7) == x)) do_slice(24);
}

// ---------------- finish: two-stage reduction ----------------

__global__ void k_red1(const float* __restrict__ ypA,
                       const float* __restrict__ ypB,
                       float* __restrict__ partial) {
    int c = blockIdx.x / 7;       // 24 chunks
    int nb = blockIdx.x % 7;
    int n = nb * 256 + threadIdx.x;
    if (n >= kL) return;
    float s = 0.0f;
    int r0 = c * 125;
    for (int i = 0; i < 125; ++i) s += ypA[(size_t)(r0 + i) * kL + n];
    for (int i = 0; i < 125; ++i) s += ypB[(size_t)(r0 + i) * kL + n];
    partial[(size_t)c * kL + n] = s;
}

__global__ void k_red2(const float* __restrict__ partial,
                       const float* __restrict__ env,
                       float* __restrict__ out) {
    int n = blockIdx.x * 256 + threadIdx.x;
    if (n >= kL) return;
    float s = 0.0f;
#pragma unroll
    for (int c = 0; c < 24; ++c) s += partial[(size_t)c * kL + n];
    float t = (float)n / kSR;
    out[n] = s * expf(env[n] - kLogGamma * t);
}

extern "C" void kernel_launch(void* const* d_in, const int* in_sizes, int n_in,
                              void* d_out, int out_size, void* d_ws, size_t ws_size,
                              hipStream_t stream) {
    const float* absorb = (const float*)d_in[0];
    const float* scat   = (const float*)d_in[1];
    const float* rad    = (const float*)d_in[2];
    const float* w      = (const float*)d_in[3];
    const float* env    = (const float*)d_in[4];
    const float* basis  = (const float*)d_in[5];
    const int*   srow   = (const int*)d_in[6];
    const int*   scol   = (const int*)d_in[7];
    const int*   srid   = (const int*)d_in[8];
    const int*   delay  = (const int*)d_in[9];

    char* ws = (char*)d_ws;
    size_t off = 0;
    auto alloc = [&](size_t bytes) -> char* {
        char* p = ws + off;
        off += (bytes + 255) & ~size_t(255);
        return p;
    };
    unsigned short* curA = (unsigned short*)alloc((size_t)kNS * kNRad * kSW * 2);
    unsigned short* curB = (unsigned short*)alloc((size_t)kNS * kNRad * kSW * 2);
    float* ypartA = (float*)alloc((size_t)3000 * kL * 4);
    float* ypartB = (float*)alloc((size_t)3000 * kL * 4);
    float* partial = (float*)alloc((size_t)24 * kL * 4);
    u32*   epack  = (u32*)alloc((size_t)kNNZ * 4);
    int*   rowptr = (int*)alloc((size_t)(kNRad + 1) * 4);
    int*   cursor = (int*)alloc((size_t)kNRad * 4);
    int*   cnt    = (int*)alloc((size_t)kNRad * 4);
    int*   perm   = (int*)alloc((size_t)kNRad * 4);
    int*   iperm  = (int*)alloc((size_t)kNRad * 4);
    float* decay  = (float*)alloc((size_t)kNRad * 4);
    int*   dmod   = (int*)alloc((size_t)kNRad * 4);
    int*   degcnt = (int*)alloc(64 * 4);
    int*   degcur = (int*)alloc(64 * 4);
    (void)ws_size; (void)in_sizes; (void)n_in; (void)out_size; (void)scol;

    hipMemsetAsync(cnt, 0, (size_t)kNRad * 4, stream);
    hipMemsetAsync(degcnt, 0, 64 * 4, stream);
    hipMemsetAsync(ypartB, 0, (size_t)3000 * kL * 4, stream);

    k_hist<<<(kNNZ + 255) / 256, 256, 0, stream>>>(srow, cnt);
    k_deghist<<<(kNRad + 255) / 256, 256, 0, stream>>>(cnt, degcnt);
    k_degscan<<<1, 64, 0, stream>>>(degcnt, degcur);
    k_perm<<<(kNRad + 255) / 256, 256, 0, stream>>>(cnt, degcur, perm, iperm);
    k_scan2<<<1, 256, 0, stream>>>(cnt, perm, rowptr, cursor);
    k_decay<<<(kNRad + 255) / 256, 256, 0, stream>>>(delay, decay, dmod);
    k_scatter<<<(kNNZ + 255) / 256, 256, 0, stream>>>(absorb, scat, basis, srow,
                                                      scol, srid, iperm, cursor, epack);

    k_init<<<3000, 64, 0, stream>>>(rad, w, decay, dmod, curA, ypartA);

    const unsigned short* in = curA;
    unsigned short* outb = curB;
    for (int b = 0; b < kNBounce; ++b) {
        k_bounce<<<3 * kNRB * 8, 256, 0, stream>>>(in, outb, ypartB, epack, rowptr,
                                                   perm, w, decay, dmod);
        const unsigned short* tmp = outb;
        outb = (unsigned short*)in;
        in = tmp;
    }

    k_red1<<<24 * 7, 256, 0, stream>>>(ypartA, ypartB, partial);
    k_red2<<<(kL + 255) / 256, 256, 0, stream>>>(partial, env, (float*)d_out);
}

// Round 9
// 2334.562 us; speedup vs baseline: 2.0109x; 1.1795x over previous
//
#include <hip/hip_runtime.h>
#include <hip/hip_fp16.h>
#include <math.h>

// AcousticRadianceTransfer v9 — time-domain, 2-sample-slice LDS SpMM.
// Rounds 2-8: random VMEM gathers pin at ~24 outstanding misses/CU ->
// 12M lines/bounce -> 185us floor (v5 sits on it). v9 moves ALL random
// access into LDS: state slice-major X[800][24000] u32 (2 bf16 samples per
// column); per bounce: k_shift (per-column circular delay via 32-col LDS
// ring, decay pre-folded into edge values, coalesced R/W) then k_slice
// (one block per slice: stage 96KB state in LDS, stream per-thread edge
// quads, ds_read_b32 gathers ~11cyc, coalesced sorted-row stores, folded
// w-contraction). Everything is sorted-index space; edges carry f16 val
// (x decay) + u16 sorted col.

static constexpr float kSR = 16000.0f;
static constexpr int   kL = 1600;
static constexpr int   kNRad = 24000;
static constexpr int   kNNZ = 480000;
static constexpr int   kNPatch = 256;
static constexpr int   kNB = 8;
static constexpr int   kNS2 = 800;           // 2-sample slices
static constexpr int   kEcap = 200;          // uint4 slots per thread (max ~149)
static constexpr float kLogGamma = -6.907755278982137f; // ln(0.001)

using u32 = unsigned int;
using u16 = unsigned short;

__device__ __forceinline__ u16 f2bf(float f) {
    u32 u = __float_as_uint(f);
    u32 r = u + 0x7fffu + ((u >> 16) & 1u);   // RTN-even
    return (u16)(r >> 16);
}
__device__ __forceinline__ float bflo(u32 w) { return __uint_as_float(w << 16); }
__device__ __forceinline__ float bfhi(u32 w) { return __uint_as_float(w & 0xffff0000u); }
__device__ __forceinline__ float bf1(u16 w) { return __uint_as_float((u32)w << 16); }
__device__ __forceinline__ u32 pk_bf(float a, float b) {
    return (u32)f2bf(a) | ((u32)f2bf(b) << 16);
}
__device__ __forceinline__ float h2f(u32 bits) {
    return __half2float(__ushort_as_half((u16)bits));
}

// ---------------- CSR build + degree sort (descending) ----------------------

__global__ void k_hist(const int* __restrict__ row, int* __restrict__ cnt) {
    int e = blockIdx.x * 256 + threadIdx.x;
    if (e < kNNZ) atomicAdd(&cnt[row[e]], 1);
}

__global__ void k_deghist(const int* __restrict__ cnt, int* __restrict__ degcnt) {
    int i = blockIdx.x * 256 + threadIdx.x;
    if (i < kNRad) atomicAdd(&degcnt[min(cnt[i], 63)], 1);
}

__global__ void k_degscan(int* __restrict__ degcnt, int* __restrict__ degcur) {
    if (threadIdx.x == 0) {
        int s = 0;
        for (int b = 63; b >= 0; --b) {          // descending degree
            int c = degcnt[b];
            degcnt[b] = s; degcur[b] = s; s += c;
        }
    }
}

__global__ void k_perm(const int* __restrict__ cnt, int* __restrict__ degcur,
                       const float* __restrict__ w, const int* __restrict__ delay,
                       int* __restrict__ perm, int* __restrict__ iperm,
                       float* __restrict__ w_s, int* __restrict__ dmod_s) {
    int i = blockIdx.x * 256 + threadIdx.x;
    if (i >= kNRad) return;
    int b = min(cnt[i], 63);
    int pos = atomicAdd(&degcur[b], 1);
    perm[pos] = i;
    iperm[i] = pos;
    w_s[pos] = w[i];
    dmod_s[pos] = delay[i] % kL;
}

__global__ void k_scan2(const int* __restrict__ cnt, const int* __restrict__ perm,
                        int* __restrict__ rowptr, int* __restrict__ cursor) {
    __shared__ int s[256];
    __shared__ int carry_s;
    int tid = threadIdx.x;
    if (tid == 0) carry_s = 0;
    __syncthreads();
    for (int base = 0; base < kNRad; base += 256) {
        int i = base + tid;
        int v = (i < kNRad) ? cnt[perm[i]] : 0;
        s[tid] = v;
        __syncthreads();
        for (int off = 1; off < 256; off <<= 1) {
            int t = (tid >= off) ? s[tid - off] : 0;
            __syncthreads();
            s[tid] += t;
            __syncthreads();
        }
        int incl = s[tid];
        int c = carry_s;
        if (i < kNRad) {
            int ex = c + incl - v;
            rowptr[i] = ex;
            cursor[i] = ex;
        }
        __syncthreads();
        if (tid == 255) carry_s = c + incl;
        __syncthreads();
    }
    if (tid == 0) rowptr[kNRad] = carry_s;
}

// decay (original index) for folding into edge values; fsm table
__global__ void k_decay(const int* __restrict__ delay,
                        float* __restrict__ decay, float* __restrict__ fsm) {
    int i = blockIdx.x * 256 + threadIdx.x;
    if (i < kNRad) decay[i] = expf(kLogGamma * (float)delay[i] / kSR);
    if (i < kL)    fsm[i] = expf(kLogGamma * (float)i / kSR);
}

// edge values: A'_rc = A_rc * decay_c ; col renumbered to sorted space
__global__ void k_scatter(const float* __restrict__ absorb,
                          const float* __restrict__ scat,
                          const float* __restrict__ basis,
                          const int* __restrict__ row,
                          const int* __restrict__ col,
                          const int* __restrict__ rid,
                          const int* __restrict__ iperm,
                          const float* __restrict__ decay,
                          int* __restrict__ cursor,
                          u32* __restrict__ epack) {
    int e = blockIdx.x * 256 + threadIdx.x;
    if (e >= kNNZ) return;
    int rd = rid[e];
    int c = col[e];
    float v = (scat[rd] * basis[e] + scat[kNPatch + rd] * basis[kNNZ + e])
              * absorb[rd] * decay[c];
    int p = iperm[row[e]];
    int pos = atomicAdd(&cursor[p], 1);
    u32 hv = (u32)__half_as_ushort(__float2half(v));
    epack[pos] = (hv << 16) | (u32)iperm[c];
}

// ---- per-(stratum,thread) quad counts + offsets (snake assignment) --------

__global__ void k_boff(const int* __restrict__ rowptr,
                       int* __restrict__ rowmeta, int* __restrict__ offT) {
    int t = threadIdx.x;   // one block of 1024
    int off = 0;
    for (int i = 0; i < 24; ++i) {
        int sidx = i * 1024 + ((i & 1) ? (1023 - t) : t);
        int nit = 0;
        if (sidx < kNRad) {
            int deg = rowptr[sidx + 1] - rowptr[sidx];
            nit = (deg + 3) >> 2;
        }
        rowmeta[i * 1024 + t] = nit;
        offT[i * 1024 + t] = off;
        off += nit;
    }
}

__global__ void k_bcopy(const int* __restrict__ rowptr,
                        const u32* __restrict__ epack,
                        const int* __restrict__ offT,
                        uint4* __restrict__ edata4) {
    int i = blockIdx.x, t = threadIdx.x;
    int sidx = i * 1024 + ((i & 1) ? (1023 - t) : t);
    if (sidx >= kNRad) return;
    int e0 = rowptr[sidx];
    int deg = rowptr[sidx + 1] - e0;
    int nit = (deg + 3) >> 2;
    int jp0 = offT[i * 1024 + t];
    for (int it = 0; it < nit; ++it) {
        u32 q[4];
#pragma unroll
        for (int c = 0; c < 4; ++c) {
            int idx = 4 * it + c;
            q[c] = (idx < deg) ? epack[e0 + idx] : 0u;
        }
        edata4[(size_t)(jp0 + it) * 1024 + t] = make_uint4(q[0], q[1], q[2], q[3]);
    }
}

// ---- init: X0[s][r'] = bf16 pair of rad[perm[r']]*fsm ; ypartA = w^T x0 ----
// 750 blocks x 1024 threads, 32 sorted rows per block, LDS ring 32x1602 u16.

__global__ __launch_bounds__(1024) void k_init0(const float* __restrict__ rad,
                                                const int* __restrict__ perm,
                                                const float* __restrict__ w_s,
                                                const float* __restrict__ fsm,
                                                u32* __restrict__ X0,
                                                float* __restrict__ ypartA) {
    extern __shared__ char smem[];
    u16* ring = (u16*)smem;                    // [32][1602]
    u32* ring32 = (u32*)smem;                  // [32][801]
    int bid = blockIdx.x, tid = threadIdx.x;
    int r0 = bid * 32;
    int k = tid >> 5, g = tid & 31;
    int orig = perm[r0 + k];
    const float* rrow = rad + (size_t)orig * kL;
    for (int it = 0; it < 50; ++it) {
        int n = it * 32 + g;
        ring[k * 1602 + n] = f2bf(rrow[n] * fsm[n]);
    }
    __syncthreads();
    // y0 partial
    for (int n = tid; n < kL; n += 1024) {
        float acc = 0.0f;
#pragma unroll
        for (int k2 = 0; k2 < 32; ++k2)
            acc = fmaf(w_s[r0 + k2], bf1(ring[k2 * 1602 + n]), acc);
        ypartA[(size_t)bid * kL + n] = acc;
    }
    // slice-major write (coalesced 128B lines)
    int si = tid >> 5, cj = tid & 31;
    for (int it = 0; it < 25; ++it) {
        int s = it * 32 + si;
        X0[(size_t)s * kNRad + r0 + cj] = ring32[cj * 801 + s];
    }
}

// ---- shift: Z[s][c] = X[c, (2s-d_c) mod L , +1] (decay already in edges) ---
// 750 blocks x 1024, 32 columns per block, LDS ring 32x1602 u16.

__global__ __launch_bounds__(1024) void k_shift(const u32* __restrict__ Xin,
                                                const int* __restrict__ dmod_s,
                                                u32* __restrict__ Zout) {
    extern __shared__ char smem[];
    u16* ring = (u16*)smem;
    u32* ring32 = (u32*)smem;
    int bid = blockIdx.x, tid = threadIdx.x;
    int c0 = bid * 32;
    int si = tid >> 5, cj = tid & 31;
    for (int it = 0; it < 25; ++it) {
        int s = it * 32 + si;
        ring32[cj * 801 + s] = Xin[(size_t)s * kNRad + c0 + cj];
    }
    __syncthreads();
    int d = dmod_s[c0 + cj];
    const u16* rc = ring + cj * 1602;
    for (int it = 0; it < 25; ++it) {
        int s = it * 32 + si;
        int m = 2 * s - d;
        if (m < 0) m += kL;
        int m2 = m + 1;
        if (m2 >= kL) m2 -= kL;
        u32 out = (u32)rc[m] | ((u32)rc[m2] << 16);
        Zout[(size_t)s * kNRad + c0 + cj] = out;
    }
}

// ---- the SpMM: one block per 2-sample slice, state in LDS ------------------

__global__ __launch_bounds__(1024) void k_slice(const u32* __restrict__ Zin,
                                                u32* __restrict__ Xout,
                                                const uint4* __restrict__ edata4,
                                                const int* __restrict__ rowmeta,
                                                const float* __restrict__ w_s,
                                                float* __restrict__ ypp) {
    extern __shared__ char smem[];
    u32* ldsx = (u32*)smem;                    // [24000]
    float* red = (float*)(ldsx + kNRad);       // [32]
    int s = blockIdx.x, tid = threadIdx.x;
    for (int c = tid; c < kNRad; c += 1024)
        ldsx[c] = Zin[(size_t)s * kNRad + c];
    __syncthreads();

    float yk0 = 0.0f, yk1 = 0.0f;
    int jp = 0;
#pragma unroll 1
    for (int i = 0; i < 24; ++i) {
        int nit = rowmeta[i * 1024 + tid];
        float a0 = 0.0f, a1 = 0.0f;
        if (nit > 0) {
            uint4 q = edata4[(size_t)jp * 1024 + tid];
            for (int it = 0; it < nit; ++it) {
                uint4 qn = edata4[(size_t)(jp + it + 1) * 1024 + tid]; // safe: kEcap margin
                u32 z0 = ldsx[q.x & 0xffffu];
                u32 z1 = ldsx[q.y & 0xffffu];
                u32 z2 = ldsx[q.z & 0xffffu];
                u32 z3 = ldsx[q.w & 0xffffu];
                float v0 = h2f(q.x >> 16), v1 = h2f(q.y >> 16);
                float v2 = h2f(q.z >> 16), v3 = h2f(q.w >> 16);
                a0 = fmaf(v0, bflo(z0), a0); a1 = fmaf(v0, bfhi(z0), a1);
                a0 = fmaf(v1, bflo(z1), a0); a1 = fmaf(v1, bfhi(z1), a1);
                a0 = fmaf(v2, bflo(z2), a0); a1 = fmaf(v2, bfhi(z2), a1);
                a0 = fmaf(v3, bflo(z3), a0); a1 = fmaf(v3, bfhi(z3), a1);
                q = qn;
            }
        }
        int row = i * 1024 + ((i & 1) ? (1023 - tid) : tid);
        if ((i < 23) || (tid >= 576)) {
            float wr = w_s[row];
            yk0 = fmaf(wr, a0, yk0);
            yk1 = fmaf(wr, a1, yk1);
            Xout[(size_t)s * kNRad + row] = pk_bf(a0, a1);
        }
        jp += nit;
    }

    // block-reduce y (2 scalars), accumulate into ypp (block-exclusive RMW)
#pragma unroll
    for (int m = 1; m <= 32; m <<= 1) {
        yk0 += __shfl_xor(yk0, m, 64);
        yk1 += __shfl_xor(yk1, m, 64);
    }
    int wv = tid >> 6, lane = tid & 63;
    if (lane == 0) { red[2 * wv] = yk0; red[2 * wv + 1] = yk1; }
    __syncthreads();
    if (tid == 0) {
        float s0 = 0.0f, s1 = 0.0f;
#pragma unroll
        for (int i = 0; i < 16; ++i) { s0 += red[2 * i]; s1 += red[2 * i + 1]; }
        ypp[2 * s] += s0;
        ypp[2 * s + 1] += s1;
    }
}

// ---- reductions / finish ----------------------------------------------------

__global__ void k_red1(const float* __restrict__ ypartA, float* __restrict__ yred) {
    int n = blockIdx.x * 256 + threadIdx.x;
    if (n >= kL) return;
    float s = 0.0f;
    for (int i = 0; i < 750; ++i) s += ypartA[(size_t)i * kL + n];
    yred[n] = s;
}

__global__ void k_final(const float* __restrict__ yred,
                        const float* __restrict__ ypp,
                        const float* __restrict__ env,
                        float* __restrict__ out) {
    int n = blockIdx.x * 256 + threadIdx.x;
    if (n >= kL) return;
    float y = yred[n] + ypp[n];
    out[n] = y * expf(env[n] - kLogGamma * (float)n / kSR);
}

extern "C" void kernel_launch(void* const* d_in, const int* in_sizes, int n_in,
                              void* d_out, int out_size, void* d_ws, size_t ws_size,
                              hipStream_t stream) {
    const float* absorb = (const float*)d_in[0];
    const float* scat   = (const float*)d_in[1];
    const float* rad    = (const float*)d_in[2];
    const float* w      = (const float*)d_in[3];
    const float* env    = (const float*)d_in[4];
    const float* basis  = (const float*)d_in[5];
    const int*   srow   = (const int*)d_in[6];
    const int*   scol   = (const int*)d_in[7];
    const int*   srid   = (const int*)d_in[8];
    const int*   delay  = (const int*)d_in[9];

    char* ws = (char*)d_ws;
    size_t off = 0;
    auto alloc = [&](size_t bytes) -> char* {
        char* p = ws + off;
        off += (bytes + 255) & ~size_t(255);
        return p;
    };
    u32*   stateA = (u32*)alloc((size_t)kNS2 * kNRad * 4);       // 76.8 MB
    u32*   stateB = (u32*)alloc((size_t)kNS2 * kNRad * 4);       // 76.8 MB
    float* ypartA = (float*)alloc((size_t)750 * kL * 4);         // 4.8 MB
    float* ypp    = (float*)alloc((size_t)kL * 4);
    float* yred   = (float*)alloc((size_t)kL * 4);
    uint4* edata4 = (uint4*)alloc((size_t)kEcap * 1024 * 16);    // 3.3 MB
    u32*   epack  = (u32*)alloc((size_t)kNNZ * 4);
    int*   rowmeta= (int*)alloc((size_t)24 * 1024 * 4);
    int*   offT   = (int*)alloc((size_t)24 * 1024 * 4);
    int*   rowptr = (int*)alloc((size_t)(kNRad + 1) * 4);
    int*   cursor = (int*)alloc((size_t)kNRad * 4);
    int*   cnt    = (int*)alloc((size_t)kNRad * 4);
    int*   perm   = (int*)alloc((size_t)kNRad * 4);
    int*   iperm  = (int*)alloc((size_t)kNRad * 4);
    float* w_s    = (float*)alloc((size_t)kNRad * 4);
    int*   dmod_s = (int*)alloc((size_t)kNRad * 4);
    float* decay  = (float*)alloc((size_t)kNRad * 4);
    float* fsm    = (float*)alloc((size_t)kL * 4);
    int*   degcnt = (int*)alloc(64 * 4);
    int*   degcur = (int*)alloc(64 * 4);
    (void)ws_size; (void)in_sizes; (void)n_in; (void)out_size; (void)scol;

    hipMemsetAsync(cnt, 0, (size_t)kNRad * 4, stream);
    hipMemsetAsync(degcnt, 0, 64 * 4, stream);
    hipMemsetAsync(ypp, 0, (size_t)kL * 4, stream);

    k_hist<<<(kNNZ + 255) / 256, 256, 0, stream>>>(srow, cnt);
    k_deghist<<<(kNRad + 255) / 256, 256, 0, stream>>>(cnt, degcnt);
    k_degscan<<<1, 64, 0, stream>>>(degcnt, degcur);
    k_perm<<<(kNRad + 255) / 256, 256, 0, stream>>>(cnt, degcur, w, delay,
                                                    perm, iperm, w_s, dmod_s);
    k_scan2<<<1, 256, 0, stream>>>(cnt, perm, rowptr, cursor);
    k_decay<<<(kNRad + 255) / 256, 256, 0, stream>>>(delay, decay, fsm);
    k_scatter<<<(kNNZ + 255) / 256, 256, 0, stream>>>(absorb, scat, basis, srow,
                                                      scol, srid, iperm, decay,
                                                      cursor, epack);
    k_boff<<<1, 1024, 0, stream>>>(rowptr, rowmeta, offT);
    k_bcopy<<<24, 1024, 0, stream>>>(rowptr, epack, offT, edata4);

    const int ringBytes = 32 * 1602 * 2;                  // 102528
    const int sliceBytes = kNRad * 4 + 32 * 4;            // 96128
    hipFuncSetAttribute((const void*)k_init0,
                        hipFuncAttributeMaxDynamicSharedMemorySize, ringBytes);
    hipFuncSetAttribute((const void*)k_shift,
                        hipFuncAttributeMaxDynamicSharedMemorySize, ringBytes);
    hipFuncSetAttribute((const void*)k_slice,
                        hipFuncAttributeMaxDynamicSharedMemorySize, sliceBytes);

    k_init0<<<750, 1024, ringBytes, stream>>>(rad, perm, w_s, fsm, stateA, ypartA);

    for (int b = 0; b < kNB; ++b) {
        k_shift<<<750, 1024, ringBytes, stream>>>(stateA, dmod_s, stateB);
        k_slice<<<kNS2, 1024, sliceBytes, stream>>>(stateB, stateA, edata4,
                                                    rowmeta, w_s, ypp);
    }

    k_red1<<<(kL + 255) / 256, 256, 0, stream>>>(ypartA, yred);
    k_final<<<(kL + 255) / 256, 256, 0, stream>>>(yred, ypp, env, (float*)d_out);
}

// Round 10
// 1602.516 us; speedup vs baseline: 2.9295x; 1.4568x over previous
//
#include <hip/hip_runtime.h>
#include <hip/hip_fp16.h>
#include <math.h>

// AcousticRadianceTransfer v10 — v5 time-domain structure (best: 1646 us),
// reverted from the nt experiment (v8: L2 thrash) and the LDS-SpMM (v9:
// single-block-per-CU overlap limit). Two safe tweaks vs v5:
//  (a) slice-24 double-duty blocks moved to phase 0 (launch first, tail hidden)
//  (b) k_init 750x256 instead of 3000x64.
// k_bounce sits on the measured architectural wall: 12.19M random 128B line
// requests per bounce (NNZ x 25 lines/row, bf16-bound) at ~0.103 lines/cyc/CU
// (~24 outstanding misses/CU), confirmed across 6 kernel structures (r2-r9).

static constexpr float kSR = 16000.0f;
static constexpr int   kL = 1600;
static constexpr int   kNRad = 24000;
static constexpr int   kNNZ = 480000;
static constexpr int   kNPatch = 256;
static constexpr int   kNBounce = 8;
static constexpr int   kSW = 64;           // samples per slice
static constexpr int   kNS = 25;           // slices
static constexpr int   kNRB = 750;         // row-blocks of 32 rows
static constexpr float kLogGamma = -6.907755278982137f; // ln(0.001)

using u32 = unsigned int;

__device__ __forceinline__ unsigned short f2bf(float f) {
    u32 u = __float_as_uint(f);
    u32 r = u + 0x7fffu + ((u >> 16) & 1u);   // RTN-even
    return (unsigned short)(r >> 16);
}
__device__ __forceinline__ float bflo(u32 w) { return __uint_as_float(w << 16); }
__device__ __forceinline__ float bfhi(u32 w) { return __uint_as_float(w & 0xffff0000u); }
__device__ __forceinline__ float h2f(u32 hv) {
    return __half2float(__ushort_as_half((unsigned short)hv));
}
__device__ __forceinline__ void fma8(float (&a)[8], float v, const uint4 q) {
    a[0] = fmaf(v, bflo(q.x), a[0]);
    a[1] = fmaf(v, bfhi(q.x), a[1]);
    a[2] = fmaf(v, bflo(q.y), a[2]);
    a[3] = fmaf(v, bfhi(q.y), a[3]);
    a[4] = fmaf(v, bflo(q.z), a[4]);
    a[5] = fmaf(v, bfhi(q.z), a[5]);
    a[6] = fmaf(v, bflo(q.w), a[6]);
    a[7] = fmaf(v, bfhi(q.w), a[7]);
}

// ---------------- CSR build + degree sort ----------------

__global__ void k_hist(const int* __restrict__ row, int* __restrict__ cnt) {
    int e = blockIdx.x * 256 + threadIdx.x;
    if (e < kNNZ) atomicAdd(&cnt[row[e]], 1);
}

__global__ void k_deghist(const int* __restrict__ cnt, int* __restrict__ degcnt) {
    int i = blockIdx.x * 256 + threadIdx.x;
    if (i < kNRad) atomicAdd(&degcnt[min(cnt[i], 63)], 1);
}

__global__ void k_degscan(int* __restrict__ degcnt, int* __restrict__ degcur) {
    if (threadIdx.x == 0) {
        int s = 0;
        for (int b = 0; b < 64; ++b) {
            int c = degcnt[b];
            degcnt[b] = s;
            degcur[b] = s;
            s += c;
        }
    }
}

__global__ void k_perm(const int* __restrict__ cnt, int* __restrict__ degcur,
                       int* __restrict__ perm, int* __restrict__ iperm) {
    int i = blockIdx.x * 256 + threadIdx.x;
    if (i >= kNRad) return;
    int b = min(cnt[i], 63);
    int pos = atomicAdd(&degcur[b], 1);
    perm[pos] = i;
    iperm[i] = pos;
}

__global__ void k_scan2(const int* __restrict__ cnt, const int* __restrict__ perm,
                        int* __restrict__ rowptr, int* __restrict__ cursor) {
    __shared__ int s[256];
    __shared__ int carry_s;
    int tid = threadIdx.x;
    if (tid == 0) carry_s = 0;
    __syncthreads();
    for (int base = 0; base < kNRad; base += 256) {
        int i = base + tid;
        int v = (i < kNRad) ? cnt[perm[i]] : 0;
        s[tid] = v;
        __syncthreads();
        for (int off = 1; off < 256; off <<= 1) {
            int t = (tid >= off) ? s[tid - off] : 0;
            __syncthreads();
            s[tid] += t;
            __syncthreads();
        }
        int incl = s[tid];
        int c = carry_s;
        if (i < kNRad) {
            int ex = c + incl - v;
            rowptr[i] = ex;
            cursor[i] = ex;
        }
        __syncthreads();
        if (tid == 255) carry_s = c + incl;
        __syncthreads();
    }
    if (tid == 0) rowptr[kNRad] = carry_s;
}

__global__ void k_scatter(const float* __restrict__ absorb,
                          const float* __restrict__ scat,
                          const float* __restrict__ basis,
                          const int* __restrict__ row,
                          const int* __restrict__ col,
                          const int* __restrict__ rid,
                          const int* __restrict__ iperm,
                          int* __restrict__ cursor,
                          u32* __restrict__ epack) {
    int e = blockIdx.x * 256 + threadIdx.x;
    if (e >= kNNZ) return;
    int rd = rid[e];
    float v = (scat[rd] * basis[e] + scat[kNPatch + rd] * basis[kNNZ + e]) * absorb[rd];
    int p = iperm[row[e]];
    int pos = atomicAdd(&cursor[p], 1);
    u32 hv = (u32)__half_as_ushort(__float2half(v));
    epack[pos] = (hv << 16) | (u32)col[e];
}

__global__ void k_decay(const int* __restrict__ delay,
                        float* __restrict__ decay, int* __restrict__ dmod) {
    int i = blockIdx.x * 256 + threadIdx.x;
    if (i >= kNRad) return;
    int d = delay[i];
    decay[i] = expf(kLogGamma * (float)d / kSR);
    dmod[i] = d % kL;
}

// ---------------- init: slice-major bf16 shifted state + ypartA --------------
// 750 blocks x 4 waves; each wave owns 8 rows; lane <-> sample-in-slice.

__global__ __launch_bounds__(256) void k_init(const float* __restrict__ rad,
                                              const float* __restrict__ w,
                                              const float* __restrict__ decay,
                                              const int* __restrict__ dmod,
                                              unsigned short* __restrict__ outS,
                                              float* __restrict__ ypartA) {
    int bid = blockIdx.x;
    int tid = threadIdx.x, wv = tid >> 6, lane = tid & 63;
    int rbase = bid * 32 + wv * 8;
    const size_t SS = (size_t)kNRad * kSW;
    for (int k = 0; k < kNS; ++k) {
        int m = k * kSW + lane;
        float fs = expf(kLogGamma * (float)m / kSR);
        float y = 0.0f;
#pragma unroll
        for (int g = 0; g < 8; ++g) {
            int r = rbase + g;
            float v = rad[(size_t)r * kL + m] * fs;
            y = fmaf(w[r], v, y);
            int n = m + dmod[r];
            if (n >= kL) n -= kL;
            outS[(size_t)(n >> 6) * SS + (size_t)r * kSW + (n & 63)] =
                f2bf(decay[r] * v);
        }
        ypartA[(size_t)(bid * 4 + wv) * kL + m] = y;
    }
}

// ---------------- one bounce, phase-major, MLP-4 edge loop ----------------
// bid = (phase*kNRB + rb)*8 + x ; slice S = x + 8*phase (phase 0..2).
// Phase-0 blocks with rb&7==x also do slice 24 (phase 0 launches first ->
// double-work blocks start earliest, tail hidden).

__global__ __launch_bounds__(256) void k_bounce(const unsigned short* __restrict__ inS,
                                                unsigned short* __restrict__ outS,
                                                float* __restrict__ ypart,
                                                const u32* __restrict__ epack,
                                                const int* __restrict__ rowptr,
                                                const int* __restrict__ perm,
                                                const float* __restrict__ w,
                                                const float* __restrict__ decay,
                                                const int* __restrict__ dmod) {
    int bid = blockIdx.x;
    int x = bid & 7;
    int t = bid >> 3;
    int phase = t / kNRB;
    int rb = t - phase * kNRB;
    int tid = threadIdx.x, wv = tid >> 6, lane = tid & 63;
    int g = lane >> 3, p = lane & 7;
    int r = rb * 32 + wv * 8 + g;
    int e0 = rowptr[r], e1 = rowptr[r + 1];
    const size_t SS = (size_t)kNRad * kSW;
    __shared__ float tb[4][8][64];

    auto do_slice = [&](int S) {
        const unsigned short* b = inS + (size_t)S * SS + (size_t)p * 8;
        float acc[8] = {0, 0, 0, 0, 0, 0, 0, 0};
        int e = e0;
        for (; e + 4 <= e1; e += 4) {
            u32 u0 = epack[e];
            u32 u1 = epack[e + 1];
            u32 u2 = epack[e + 2];
            u32 u3 = epack[e + 3];
            uint4 q0 = *(const uint4*)(b + (size_t)(u0 & 0xffffu) * kSW);
            uint4 q1 = *(const uint4*)(b + (size_t)(u1 & 0xffffu) * kSW);
            uint4 q2 = *(const uint4*)(b + (size_t)(u2 & 0xffffu) * kSW);
            uint4 q3 = *(const uint4*)(b + (size_t)(u3 & 0xffffu) * kSW);
            fma8(acc, h2f(u0 >> 16), q0);
            fma8(acc, h2f(u1 >> 16), q1);
            fma8(acc, h2f(u2 >> 16), q2);
            fma8(acc, h2f(u3 >> 16), q3);
        }
        for (; e < e1; ++e) {
            u32 u = epack[e];
            uint4 q = *(const uint4*)(b + (size_t)(u & 0xffffu) * kSW);
            fma8(acc, h2f(u >> 16), q);
        }
        // LDS transpose -> wave-contiguous shifted+decayed stores + y reduce
#pragma unroll
        for (int i = 0; i < 8; ++i) tb[wv][g][p * 8 + i] = acc[i];
        float yk = 0.0f;
#pragma unroll
        for (int g2 = 0; g2 < 8; ++g2) {
            int o2 = perm[rb * 32 + wv * 8 + g2];
            float val = tb[wv][g2][lane];
            yk = fmaf(w[o2], val, yk);
            int n = S * kSW + lane + dmod[o2];
            if (n >= kL) n -= kL;
            if (n >= kL) n -= kL;
            outS[(size_t)(n >> 6) * SS + (size_t)o2 * kSW + (n & 63)] =
                f2bf(decay[o2] * val);
        }
        ypart[((size_t)(rb * 4 + wv)) * kL + S * kSW + lane] += yk;
    };

    do_slice(x + 8 * phase);
    if (phase == 0 && ((rb & 7) == x)) do_slice(24);
}

// ---------------- finish: two-stage reduction ----------------

__global__ void k_red1(const float* __restrict__ ypA,
                       const float* __restrict__ ypB,
                       float* __restrict__ partial) {
    int c = blockIdx.x / 7;       // 24 chunks
    int nb = blockIdx.x % 7;
    int n = nb * 256 + threadIdx.x;
    if (n >= kL) return;
    float s = 0.0f;
    int r0 = c * 125;
    for (int i = 0; i < 125; ++i) s += ypA[(size_t)(r0 + i) * kL + n];
    for (int i = 0; i < 125; ++i) s += ypB[(size_t)(r0 + i) * kL + n];
    partial[(size_t)c * kL + n] = s;
}

__global__ void k_red2(const float* __restrict__ partial,
                       const float* __restrict__ env,
                       float* __restrict__ out) {
    int n = blockIdx.x * 256 + threadIdx.x;
    if (n >= kL) return;
    float s = 0.0f;
#pragma unroll
    for (int c = 0; c < 24; ++c) s += partial[(size_t)c * kL + n];
    float t = (float)n / kSR;
    out[n] = s * expf(env[n] - kLogGamma * t);
}

extern "C" void kernel_launch(void* const* d_in, const int* in_sizes, int n_in,
                              void* d_out, int out_size, void* d_ws, size_t ws_size,
                              hipStream_t stream) {
    const float* absorb = (const float*)d_in[0];
    const float* scat   = (const float*)d_in[1];
    const float* rad    = (const float*)d_in[2];
    const float* w      = (const float*)d_in[3];
    const float* env    = (const float*)d_in[4];
    const float* basis  = (const float*)d_in[5];
    const int*   srow   = (const int*)d_in[6];
    const int*   scol   = (const int*)d_in[7];
    const int*   srid   = (const int*)d_in[8];
    const int*   delay  = (const int*)d_in[9];

    char* ws = (char*)d_ws;
    size_t off = 0;
    auto alloc = [&](size_t bytes) -> char* {
        char* p = ws + off;
        off += (bytes + 255) & ~size_t(255);
        return p;
    };
    unsigned short* curA = (unsigned short*)alloc((size_t)kNS * kNRad * kSW * 2);
    unsigned short* curB = (unsigned short*)alloc((size_t)kNS * kNRad * kSW * 2);
    float* ypartA = (float*)alloc((size_t)3000 * kL * 4);
    float* ypartB = (float*)alloc((size_t)3000 * kL * 4);
    float* partial = (float*)alloc((size_t)24 * kL * 4);
    u32*   epack  = (u32*)alloc((size_t)kNNZ * 4);
    int*   rowptr = (int*)alloc((size_t)(kNRad + 1) * 4);
    int*   cursor = (int*)alloc((size_t)kNRad * 4);
    int*   cnt    = (int*)alloc((size_t)kNRad * 4);
    int*   perm   = (int*)alloc((size_t)kNRad * 4);
    int*   iperm  = (int*)alloc((size_t)kNRad * 4);
    float* decay  = (float*)alloc((size_t)kNRad * 4);
    int*   dmod   = (int*)alloc((size_t)kNRad * 4);
    int*   degcnt = (int*)alloc(64 * 4);
    int*   degcur = (int*)alloc(64 * 4);
    (void)ws_size; (void)in_sizes; (void)n_in; (void)out_size; (void)scol;

    hipMemsetAsync(cnt, 0, (size_t)kNRad * 4, stream);
    hipMemsetAsync(degcnt, 0, 64 * 4, stream);
    hipMemsetAsync(ypartB, 0, (size_t)3000 * kL * 4, stream);

    k_hist<<<(kNNZ + 255) / 256, 256, 0, stream>>>(srow, cnt);
    k_deghist<<<(kNRad + 255) / 256, 256, 0, stream>>>(cnt, degcnt);
    k_degscan<<<1, 64, 0, stream>>>(degcnt, degcur);
    k_perm<<<(kNRad + 255) / 256, 256, 0, stream>>>(cnt, degcur, perm, iperm);
    k_scan2<<<1, 256, 0, stream>>>(cnt, perm, rowptr, cursor);
    k_decay<<<(kNRad + 255) / 256, 256, 0, stream>>>(delay, decay, dmod);
    k_scatter<<<(kNNZ + 255) / 256, 256, 0, stream>>>(absorb, scat, basis, srow,
                                                      scol, srid, iperm, cursor, epack);

    k_init<<<kNRB, 256, 0, stream>>>(rad, w, decay, dmod, curA, ypartA);

    const unsigned short* in = curA;
    unsigned short* outb = curB;
    for (int b = 0; b < kNBounce; ++b) {
        k_bounce<<<3 * kNRB * 8, 256, 0, stream>>>(in, outb, ypartB, epack, rowptr,
                                                   perm, w, decay, dmod);
        const unsigned short* tmp = outb;
        outb = (unsigned short*)in;
        in = tmp;
    }

    k_red1<<<24 * 7, 256, 0, stream>>>(ypartA, ypartB, partial);
    k_red2<<<(kL + 255) / 256, 256, 0, stream>>>(partial, env, (float*)d_out);
}